// Round 10
// baseline (576.662 us; speedup 1.0000x reference)
//
#include <hip/hip_runtime.h>
#include <hip/hip_bf16.h>
#include <math.h>

#define DIM 128

typedef __attribute__((ext_vector_type(8))) short bf16x8;
typedef __attribute__((ext_vector_type(4))) float f32x4;

__device__ __forceinline__ ushort f2bf(float f) {  // RTNE
  unsigned u = __float_as_uint(f);
  return (ushort)((u + 0x7FFFu + ((u >> 16) & 1u)) >> 16);
}
__device__ __forceinline__ float bf2f(ushort h) {
  return __uint_as_float(((unsigned)h) << 16);
}

// ---------------- fused prep: hist_rank || cast || wsplit, INTERLEAVED ----------------
__global__ __launch_bounds__(256) void prep_kernel(
    const int* __restrict__ dst, unsigned* __restrict__ deg, unsigned* __restrict__ rank, int E,
    const float* __restrict__ x, ushort* __restrict__ xh, long total,
    const float* __restrict__ W1l, const float* __restrict__ W1r,
    const float* __restrict__ W2l, const float* __restrict__ W2r,
    ushort* __restrict__ tabs, int H, int C) {
  const int bid = blockIdx.x;
  const int r = bid % 3;
  const int q = bid / 3;
  if (r == 0) {
    if (q < H) {
      int gid = q * 256 + threadIdx.x;
      if (gid < E) rank[gid] = atomicAdd(&deg[dst[gid]], 1u);
    }
    return;
  }
  int id2 = q * 2 + (r - 1);
  if (id2 < C) {
    long i = ((long)id2 * 256 + threadIdx.x) * 4;
    if (i >= total) return;
    float4 v = *(const float4*)(x + i);
    uint2 Hh;
    Hh.x = (unsigned)f2bf(v.x) | ((unsigned)f2bf(v.y) << 16);
    Hh.y = (unsigned)f2bf(v.z) | ((unsigned)f2bf(v.w) << 16);
    *(uint2*)(xh + i) = Hh;
    return;
  }
  id2 -= C;
  if (id2 >= 256) return;
  int m = id2 >> 6;
  const float* W = (m == 0) ? W1l : (m == 1) ? W1r : (m == 2) ? W2l : W2r;
  ushort* Ht = tabs + (size_t)m * 32768;
  ushort* Lt = Ht + 16384;
  int idx = (id2 & 63) * 256 + threadIdx.x;  // 0..16383
  int k = idx >> 7, n = idx & 127;
  float v = W[idx];
  ushort h = f2bf(v);
  Ht[n * DIM + k] = h;
  Lt[n * DIM + k] = f2bf(v - bf2f(h));
}

// ---------------- two-level exclusive scan over deg (+ fused dinv) ----------------
__global__ __launch_bounds__(256) void scan_block_kernel(const unsigned* __restrict__ deg,
                                                         unsigned* __restrict__ excl,
                                                         unsigned* __restrict__ partial,
                                                         float* __restrict__ dinv, int N) {
  __shared__ unsigned s[256];
  int i = blockIdx.x * 256 + threadIdx.x;
  unsigned v = (i < N) ? deg[i] : 0u;
  if (i < N) dinv[i] = 1.0f / fmaxf((float)v, 1.0f);
  s[threadIdx.x] = v;
  __syncthreads();
#pragma unroll
  for (int d = 1; d < 256; d <<= 1) {
    unsigned t = (threadIdx.x >= d) ? s[threadIdx.x - d] : 0u;
    __syncthreads();
    s[threadIdx.x] += t;
    __syncthreads();
  }
  if (i < N) excl[i] = s[threadIdx.x] - v;
  if (threadIdx.x == 255) partial[blockIdx.x] = s[255];
}

__global__ __launch_bounds__(256) void scan_partials_kernel(unsigned* __restrict__ partial, int B) {
  __shared__ unsigned s[256];
  __shared__ unsigned carry;
  if (threadIdx.x == 0) carry = 0u;
  __syncthreads();
  for (int base = 0; base < B; base += 256) {
    int i = base + threadIdx.x;
    unsigned v = (i < B) ? partial[i] : 0u;
    s[threadIdx.x] = v;
    __syncthreads();
#pragma unroll
    for (int d = 1; d < 256; d <<= 1) {
      unsigned t = (threadIdx.x >= d) ? s[threadIdx.x - d] : 0u;
      __syncthreads();
      s[threadIdx.x] += t;
      __syncthreads();
    }
    if (i < B) partial[i] = carry + s[threadIdx.x] - v;
    __syncthreads();
    if (threadIdx.x == 0) carry += s[255];
    __syncthreads();
  }
}

__global__ __launch_bounds__(256) void add_offsets_kernel(const unsigned* __restrict__ excl,
                                                          const unsigned* __restrict__ partial,
                                                          unsigned* __restrict__ off, int N, int E) {
  int i = blockIdx.x * 256 + threadIdx.x;
  if (i < N) off[i] = excl[i] + partial[i >> 8];
  if (i == N) off[N] = (unsigned)E;
}

// ---------------- CSR fill: atomic-free ----------------
__global__ __launch_bounds__(256) void csr_fill_kernel(const int* __restrict__ src,
                                                       const int* __restrict__ dst,
                                                       const unsigned* __restrict__ rank,
                                                       const unsigned* __restrict__ off,
                                                       int* __restrict__ csr_src, int E) {
  int e = blockIdx.x * 256 + threadIdx.x;
  if (e >= E) return;
  csr_src[off[dst[e]] + rank[e]] = src[e];
}

// ---------------- FUSED SAGE layer: gather -> LDS -> MFMA (+ optional lin3 -> y) ----------------
// Phase 1: wave-per-node gather of this block's 128 rows, bf16 quantized, written directly
//          into the swizzled LDS A-tile (AsG, 32 KB). agg never touches global memory.
// Phase 2: agg @ (WlH + WlL), Bs staged per 64-k round (16 KB).
// Phase 3: x @ (WrH + WrL); x-tile aliases AsG[0..16K) (dead after phase 2).
// Peak LDS 48 KB -> 3 blocks/CU; inter-block overlap hides gather latency under MFMA.
// NOT in-place (other blocks' gathers read neighbor rows concurrently): ping-pong buffers.
__global__ __launch_bounds__(256) void sage_fused_kernel(
    const ushort* __restrict__ xin, const int* __restrict__ csr_src,
    const unsigned* __restrict__ off, const float* __restrict__ dinv,
    const ushort* __restrict__ WlH, const ushort* __restrict__ WlL,
    const ushort* __restrict__ WrH, const ushort* __restrict__ WrL,
    const float* __restrict__ bias,
    const float* __restrict__ W3l, const float* __restrict__ W3r,
    ushort* __restrict__ outH, float* __restrict__ y, int N) {
  __shared__ ushort AsG[128 * 128];  // 32 KB: [half][row][64-k], halves at 0 / 8192
  __shared__ ushort Bs[128 * 64];    // 16 KB

  const int tid = threadIdx.x;
  const int bm = blockIdx.x * 128;
  const int wave = tid >> 6;
  const int lane = tid & 63;
  const int l15 = lane & 15;
  const int quad = lane >> 4;
  const int wm = wave >> 1;
  const int wn = wave & 1;

  // ---------- phase 1: gather this block's 128 rows (wave-per-node, 32 iters) ----------
  {
    const int eslot = lane >> 4;
    const int col = lane & 15;
    const ushort* fbase = xin + col * 8;
    for (int it = 0; it < 32; ++it) {
      const int nl = it * 4 + wave;
      int cn = bm + nl;
      if (cn >= N) cn = N - 1;
      const unsigned beg = off[cn], end = off[cn + 1];
      float acc[8];
#pragma unroll
      for (int t = 0; t < 8; ++t) acc[t] = 0.f;
      auto accum = [&](int4 v) {
        unsigned w0 = (unsigned)v.x, w1 = (unsigned)v.y, w2 = (unsigned)v.z, w3 = (unsigned)v.w;
        acc[0] += __uint_as_float(w0 << 16);
        acc[1] += __uint_as_float(w0 & 0xFFFF0000u);
        acc[2] += __uint_as_float(w1 << 16);
        acc[3] += __uint_as_float(w1 & 0xFFFF0000u);
        acc[4] += __uint_as_float(w2 << 16);
        acc[5] += __uint_as_float(w2 & 0xFFFF0000u);
        acc[6] += __uint_as_float(w3 << 16);
        acc[7] += __uint_as_float(w3 & 0xFFFF0000u);
      };
      unsigned base = beg;
      for (; base + 16 <= end; base += 16) {
        int s0 = csr_src[base + eslot];
        int s1 = csr_src[base + 4 + eslot];
        int s2 = csr_src[base + 8 + eslot];
        int s3 = csr_src[base + 12 + eslot];
        int4 v0 = *(const int4*)(fbase + (size_t)s0 * DIM);
        int4 v1 = *(const int4*)(fbase + (size_t)s1 * DIM);
        int4 v2 = *(const int4*)(fbase + (size_t)s2 * DIM);
        int4 v3 = *(const int4*)(fbase + (size_t)s3 * DIM);
        accum(v0); accum(v1); accum(v2); accum(v3);
      }
      for (; base + 8 <= end; base += 8) {
        int s0 = csr_src[base + eslot];
        int s1 = csr_src[base + 4 + eslot];
        int4 v0 = *(const int4*)(fbase + (size_t)s0 * DIM);
        int4 v1 = *(const int4*)(fbase + (size_t)s1 * DIM);
        accum(v0); accum(v1);
      }
      for (unsigned e = base + eslot; e < end; e += 4) {
        int s = csr_src[e];
        int4 v = *(const int4*)(fbase + (size_t)s * DIM);
        accum(v);
      }
#pragma unroll
      for (int t = 0; t < 8; ++t) {
        acc[t] += __shfl_xor(acc[t], 32, 64);
        acc[t] += __shfl_xor(acc[t], 16, 64);
      }
      if (eslot == 0) {
        float di = dinv[cn];
        unsigned ph[4];
#pragma unroll
        for (int t = 0; t < 4; ++t)
          ph[t] = (unsigned)f2bf(acc[2 * t] * di) | ((unsigned)f2bf(acc[2 * t + 1] * di) << 16);
        int half = col >> 3, kg = col & 7;
        *(int4*)(&AsG[half * 8192 + nl * 64 + ((kg ^ (nl & 7)) << 3)]) =
            make_int4((int)ph[0], (int)ph[1], (int)ph[2], (int)ph[3]);
      }
    }
  }

  f32x4 acc[4][4];
#pragma unroll
  for (int i = 0; i < 4; ++i)
#pragma unroll
    for (int j = 0; j < 4; ++j) acc[i][j] = (f32x4){0.f, 0.f, 0.f, 0.f};

  auto stageB = [&](const ushort* Wp, int kt) {
#pragma unroll
    for (int c = 0; c < 4; ++c) {
      int flat = c * 256 + tid;
      int row = flat >> 3, kg = flat & 7;
      *(int4*)(&Bs[row * 64 + ((kg ^ (row & 7)) << 3)]) =
          *(const int4*)(Wp + (size_t)row * DIM + kt + kg * 8);
    }
  };
  auto mfma32 = [&](const ushort* Ab) {
#pragma unroll
    for (int ks = 0; ks < 2; ++ks) {
      bf16x8 af[4], bfr[4];
      int kg = (ks << 2) + quad;
#pragma unroll
      for (int i = 0; i < 4; ++i) {
        int ar = (wm << 6) + (i << 4) + l15;
        af[i] = *(const bf16x8*)(&Ab[ar * 64 + ((kg ^ (ar & 7)) << 3)]);
        int br = (wn << 6) + (i << 4) + l15;
        bfr[i] = *(const bf16x8*)(&Bs[br * 64 + ((kg ^ (br & 7)) << 3)]);
      }
#pragma unroll
      for (int i = 0; i < 4; ++i)
#pragma unroll
        for (int j = 0; j < 4; ++j)
          acc[i][j] = __builtin_amdgcn_mfma_f32_16x16x32_bf16(af[i], bfr[j], acc[i][j], 0, 0, 0);
    }
  };

  __syncthreads();  // gather writes visible

  // ---------- phase 2: agg @ Wl (H then L) ----------
  for (int t = 0; t < 2; ++t) {
    const ushort* Wp = t ? WlL : WlH;
    for (int ktb = 0; ktb < 2; ++ktb) {
      if (t || ktb) __syncthreads();  // protect previous round's Bs reads
      stageB(Wp, ktb << 6);
      __syncthreads();
      mfma32(&AsG[ktb * 8192]);
    }
  }

  // ---------- phase 3: x @ Wr (Ax aliases AsG[0..16K)) ----------
  ushort* Ax = AsG;
  for (int ktb = 0; ktb < 2; ++ktb) {
    __syncthreads();  // all prior LDS reads (incl. AsG half0) done
#pragma unroll
    for (int c = 0; c < 4; ++c) {
      int flat = c * 256 + tid;
      int row = flat >> 3, kg = flat & 7;
      int grow = bm + row;
      if (grow >= N) grow = N - 1;
      *(int4*)(&Ax[row * 64 + ((kg ^ (row & 7)) << 3)]) =
          *(const int4*)(xin + (size_t)grow * DIM + (ktb << 6) + kg * 8);
    }
    stageB(WrH, ktb << 6);
    __syncthreads();
    mfma32(Ax);
    __syncthreads();
    stageB(WrL, ktb << 6);
    __syncthreads();
    mfma32(Ax);
  }

  __syncthreads();  // all LDS dead; alias epilogue buffers onto AsG
  float* WcF = reinterpret_cast<float*>(AsG);        // [128][4] = 2 KB
  float* YpF = reinterpret_cast<float*>(AsG) + 512;  // [128][4][2] = 4 KB

  if (W3l) {
    for (int t = tid; t < 512; t += 256) {
      int col = t >> 2, c = t & 3;
      WcF[t] = (c < 2) ? W3l[col * 2 + c] : W3r[col * 2 + (c - 2)];
    }
    __syncthreads();
  }

  float bv[4];
#pragma unroll
  for (int j = 0; j < 4; ++j) bv[j] = bias[(wn << 6) + (j << 4) + l15];

#pragma unroll
  for (int i = 0; i < 4; ++i) {
#pragma unroll
    for (int r = 0; r < 4; ++r) {
      const int rowl = (wm << 6) + (i << 4) + (quad << 2) + r;
      const int grow = bm + rowl;
      float p0 = 0.f, p1 = 0.f, p2 = 0.f, p3 = 0.f;
#pragma unroll
      for (int j = 0; j < 4; ++j) {
        float v = fmaxf(acc[i][j][r] + bv[j], 0.f);
        ushort h = f2bf(v);
        if (outH && grow < N) outH[(size_t)grow * DIM + (wn << 6) + (j << 4) + l15] = h;
        if (W3l) {
          float qv = bf2f(h);
          int col = (wn << 6) + (j << 4) + l15;
          p0 += qv * WcF[col * 4 + 0];
          p1 += qv * WcF[col * 4 + 1];
          p2 += qv * WcF[col * 4 + 2];
          p3 += qv * WcF[col * 4 + 3];
        }
      }
      if (W3l) {
#pragma unroll
        for (int o = 1; o < 16; o <<= 1) {
          p0 += __shfl_xor(p0, o, 64);
          p1 += __shfl_xor(p1, o, 64);
          p2 += __shfl_xor(p2, o, 64);
          p3 += __shfl_xor(p3, o, 64);
        }
        if (l15 == 0) {
          YpF[(rowl * 4 + 0) * 2 + wn] = p0;
          YpF[(rowl * 4 + 1) * 2 + wn] = p1;
          YpF[(rowl * 4 + 2) * 2 + wn] = p2;
          YpF[(rowl * 4 + 3) * 2 + wn] = p3;
        }
      }
    }
  }

  if (W3l) {
    __syncthreads();
    for (int t = tid; t < 512; t += 256) {
      int grow = bm + (t >> 2);
      if (grow < N) y[(size_t)grow * 4 + (t & 3)] = YpF[t * 2 + 0] + YpF[t * 2 + 1];
    }
  }
}

// ---------------- layer 3: 2-dim CSR gather + bias + relu + log_softmax ----------------
__global__ __launch_bounds__(256) void final3_kernel(const float* __restrict__ y,
                                                     const int* __restrict__ csr_src,
                                                     const unsigned* __restrict__ off,
                                                     const float* __restrict__ dinv,
                                                     const float* __restrict__ b3,
                                                     float* __restrict__ out, int N) {
  int n = blockIdx.x * 256 + threadIdx.x;
  if (n >= N) return;
  unsigned beg = off[n], end = off[n + 1];
  float s0 = 0.f, s1 = 0.f;
  for (unsigned e = beg; e < end; ++e) {
    int s = csr_src[e];
    float2 v = *reinterpret_cast<const float2*>(&y[(size_t)s * 4]);
    s0 += v.x; s1 += v.y;
  }
  float di = dinv[n];
  float o0 = fmaxf(s0 * di + y[(size_t)n * 4 + 2] + b3[0], 0.f);
  float o1 = fmaxf(s1 * di + y[(size_t)n * 4 + 3] + b3[1], 0.f);
  float m = fmaxf(o0, o1);
  float l = m + logf(expf(o0 - m) + expf(o1 - m));
  out[n * 2 + 0] = o0 - l;
  out[n * 2 + 1] = o1 - l;
}

extern "C" void kernel_launch(void* const* d_in, const int* in_sizes, int n_in,
                              void* d_out, int out_size, void* d_ws, size_t ws_size,
                              hipStream_t stream) {
  const float* x   = (const float*)d_in[0];
  const int*   ei  = (const int*)d_in[1];
  const float* W1l = (const float*)d_in[2];
  const float* W1r = (const float*)d_in[3];
  const float* b1  = (const float*)d_in[4];
  const float* W2l = (const float*)d_in[5];
  const float* W2r = (const float*)d_in[6];
  const float* b2  = (const float*)d_in[7];
  const float* W3l = (const float*)d_in[8];
  const float* W3r = (const float*)d_in[9];
  const float* b3  = (const float*)d_in[10];

  const int N = in_sizes[0] / DIM;  // 100000
  const int E = in_sizes[1] / 2;    // 1600000
  const int* src = ei;
  const int* dst = ei + E;
  const int B = (N + 255) / 256;

  char* ws = (char*)d_ws;
  size_t off_b = 0;
  auto alloc = [&](size_t bytes) {
    void* p = ws + off_b;
    off_b = (off_b + bytes + 255) & ~(size_t)255;
    return p;
  };
  unsigned* deg     = (unsigned*)alloc((size_t)N * 4);
  unsigned* excl    = (unsigned*)alloc((size_t)N * 4);
  unsigned* partial = (unsigned*)alloc((size_t)B * 4);
  unsigned* offs    = (unsigned*)alloc((size_t)(N + 1) * 4);
  unsigned* rank    = (unsigned*)alloc((size_t)E * 4);
  int*      csr_src = (int*)alloc((size_t)E * 4);
  float*    dinv    = (float*)alloc((size_t)N * 4);
  ushort*   xH      = (ushort*)alloc((size_t)N * DIM * 2);
  ushort*   hbuf    = (ushort*)alloc((size_t)N * DIM * 2);
  ushort*   wtabs   = (ushort*)alloc((size_t)8 * 16384 * 2);
  float*    y       = (float*)alloc((size_t)N * 4 * 4);

  // ---- fused prep: hist_rank || cast || wsplit, interleaved ----
  const int H = (E + 255) / 256;                           // 6250
  const int C = (int)(((size_t)N * DIM / 4 + 255) / 256);  // 12500
  const int third = (H > (C + 257) / 2) ? H : (C + 257) / 2;
  hipMemsetAsync(deg, 0, (size_t)N * 4, stream);
  prep_kernel<<<third * 3, 256, 0, stream>>>(dst, deg, rank, E, x, xH, (long)N * DIM,
                                             W1l, W1r, W2l, W2r, wtabs, H, C);

  // ---- scan + fill ----
  scan_block_kernel<<<B, 256, 0, stream>>>(deg, excl, partial, dinv, N);
  scan_partials_kernel<<<1, 256, 0, stream>>>(partial, B);
  add_offsets_kernel<<<(N + 256) / 256, 256, 0, stream>>>(excl, partial, offs, N, E);
  csr_fill_kernel<<<(E + 255) / 256, 256, 0, stream>>>(src, dst, rank, offs, csr_src, E);

  const ushort* W1lH = wtabs;           const ushort* W1lL = wtabs + 16384;
  const ushort* W1rH = wtabs + 32768;   const ushort* W1rL = wtabs + 49152;
  const ushort* W2lH = wtabs + 65536;   const ushort* W2lL = wtabs + 81920;
  const ushort* W2rH = wtabs + 98304;   const ushort* W2rL = wtabs + 114688;

  const int gemm_grid = (N + 127) / 128;

  // ---- layer 1: xH -> hbuf (fused gather+GEMM) ----
  sage_fused_kernel<<<gemm_grid, 256, 0, stream>>>(xH, csr_src, offs, dinv,
                                                   W1lH, W1lL, W1rH, W1rL, b1,
                                                   nullptr, nullptr, hbuf, nullptr, N);
  // ---- layer 2: hbuf -> y only (h2 store eliminated; fused lin3) ----
  sage_fused_kernel<<<gemm_grid, 256, 0, stream>>>(hbuf, csr_src, offs, dinv,
                                                   W2lH, W2lL, W2rH, W2rL, b2,
                                                   W3l, W3r, nullptr, y, N);
  // ---- layer 3 ----
  final3_kernel<<<(N + 255) / 256, 256, 0, stream>>>(y, csr_src, offs, dinv, b3, (float*)d_out, N);
}

// Round 11
// 432.707 us; speedup vs baseline: 1.3327x; 1.3327x over previous
//
#include <hip/hip_runtime.h>
#include <hip/hip_bf16.h>
#include <math.h>

#define DIM 128

typedef __attribute__((ext_vector_type(8))) short bf16x8;
typedef __attribute__((ext_vector_type(4))) float f32x4;

__device__ __forceinline__ ushort f2bf(float f) {  // RTNE
  unsigned u = __float_as_uint(f);
  return (ushort)((u + 0x7FFFu + ((u >> 16) & 1u)) >> 16);
}
__device__ __forceinline__ float bf2f(ushort h) {
  return __uint_as_float(((unsigned)h) << 16);
}

// ---------------- fused prep: hist_rank || cast || wsplit, INTERLEAVED ----------------
__global__ __launch_bounds__(256) void prep_kernel(
    const int* __restrict__ dst, unsigned* __restrict__ deg, unsigned* __restrict__ rank, int E,
    const float* __restrict__ x, ushort* __restrict__ xh, long total,
    const float* __restrict__ W1l, const float* __restrict__ W1r,
    const float* __restrict__ W2l, const float* __restrict__ W2r,
    ushort* __restrict__ tabs, int H, int C) {
  const int bid = blockIdx.x;
  const int r = bid % 3;
  const int q = bid / 3;
  if (r == 0) {
    if (q < H) {
      int gid = q * 256 + threadIdx.x;
      if (gid < E) rank[gid] = atomicAdd(&deg[dst[gid]], 1u);
    }
    return;
  }
  int id2 = q * 2 + (r - 1);
  if (id2 < C) {
    long i = ((long)id2 * 256 + threadIdx.x) * 4;
    if (i >= total) return;
    float4 v = *(const float4*)(x + i);
    uint2 Hh;
    Hh.x = (unsigned)f2bf(v.x) | ((unsigned)f2bf(v.y) << 16);
    Hh.y = (unsigned)f2bf(v.z) | ((unsigned)f2bf(v.w) << 16);
    *(uint2*)(xh + i) = Hh;
    return;
  }
  id2 -= C;
  if (id2 >= 256) return;
  int m = id2 >> 6;
  const float* W = (m == 0) ? W1l : (m == 1) ? W1r : (m == 2) ? W2l : W2r;
  ushort* Ht = tabs + (size_t)m * 32768;
  ushort* Lt = Ht + 16384;
  int idx = (id2 & 63) * 256 + threadIdx.x;  // 0..16383
  int k = idx >> 7, n = idx & 127;
  float v = W[idx];
  ushort h = f2bf(v);
  Ht[n * DIM + k] = h;
  Lt[n * DIM + k] = f2bf(v - bf2f(h));
}

// ---------------- two-level exclusive scan over deg (+ fused dinv) ----------------
__global__ __launch_bounds__(256) void scan_block_kernel(const unsigned* __restrict__ deg,
                                                         unsigned* __restrict__ excl,
                                                         unsigned* __restrict__ partial,
                                                         float* __restrict__ dinv, int N) {
  __shared__ unsigned s[256];
  int i = blockIdx.x * 256 + threadIdx.x;
  unsigned v = (i < N) ? deg[i] : 0u;
  if (i < N) dinv[i] = 1.0f / fmaxf((float)v, 1.0f);
  s[threadIdx.x] = v;
  __syncthreads();
#pragma unroll
  for (int d = 1; d < 256; d <<= 1) {
    unsigned t = (threadIdx.x >= d) ? s[threadIdx.x - d] : 0u;
    __syncthreads();
    s[threadIdx.x] += t;
    __syncthreads();
  }
  if (i < N) excl[i] = s[threadIdx.x] - v;
  if (threadIdx.x == 255) partial[blockIdx.x] = s[255];
}

__global__ __launch_bounds__(256) void scan_partials_kernel(unsigned* __restrict__ partial, int B) {
  __shared__ unsigned s[256];
  __shared__ unsigned carry;
  if (threadIdx.x == 0) carry = 0u;
  __syncthreads();
  for (int base = 0; base < B; base += 256) {
    int i = base + threadIdx.x;
    unsigned v = (i < B) ? partial[i] : 0u;
    s[threadIdx.x] = v;
    __syncthreads();
#pragma unroll
    for (int d = 1; d < 256; d <<= 1) {
      unsigned t = (threadIdx.x >= d) ? s[threadIdx.x - d] : 0u;
      __syncthreads();
      s[threadIdx.x] += t;
      __syncthreads();
    }
    if (i < B) partial[i] = carry + s[threadIdx.x] - v;
    __syncthreads();
    if (threadIdx.x == 0) carry += s[255];
    __syncthreads();
  }
}

// ---------------- fused: csr_fill || add_offsets || hr1 = xH @ (W1rH+W1rL) ----------------
// Role-split (lesson from R10: fuse latency-bound + MFMA work via DIFFERENT blocks, not
// phases). bid%6<5 -> fill (atomic-free, inline offsets); bid%6==5 -> q<G: 128-row GEMM
// tile writing hr1 bf16 (no bias/relu); G<=q<G+A: write off[] for later kernels.
__global__ __launch_bounds__(256) void fill_linr_kernel(
    const int* __restrict__ src, const int* __restrict__ dst,
    const unsigned* __restrict__ rank, const unsigned* __restrict__ excl,
    const unsigned* __restrict__ partial, unsigned* __restrict__ off,
    int* __restrict__ csr_src, int E, int N,
    const ushort* __restrict__ xH, const ushort* __restrict__ WrH,
    const ushort* __restrict__ WrL, ushort* __restrict__ hr, int G, int A) {
  __shared__ ushort As[128 * 64];  // 16 KB
  __shared__ ushort Bs[128 * 64];  // 16 KB

  const int bid = blockIdx.x;
  const int r = bid % 6;
  const int q = bid / 6;
  const int tid = threadIdx.x;

  if (r < 5) {  // ---- csr_fill role ----
    int fid = q * 5 + r;
    int e = fid * 256 + tid;
    if (e < E) {
      int d = dst[e];
      csr_src[excl[d] + partial[d >> 8] + rank[e]] = src[e];
    }
    return;
  }
  if (q >= G) {  // ---- add_offsets role ----
    int qa = q - G;
    if (qa < A) {
      int i = qa * 256 + tid;
      if (i < N) off[i] = excl[i] + partial[i >> 8];
      if (i == N) off[N] = (unsigned)E;
    }
    return;
  }

  // ---- GEMM role: hr[bm..bm+127] = xH @ (WrH + WrL), bf16, no bias/relu ----
  const int bm = q * 128;
  const int wave = tid >> 6;
  const int lane = tid & 63;
  const int l15 = lane & 15;
  const int quad = lane >> 4;
  const int wm = wave >> 1;
  const int wn = wave & 1;

  f32x4 acc[4][4];
#pragma unroll
  for (int i = 0; i < 4; ++i)
#pragma unroll
    for (int j = 0; j < 4; ++j) acc[i][j] = (f32x4){0.f, 0.f, 0.f, 0.f};

  for (int t = 0; t < 2; ++t) {
    const ushort* Wp = t ? WrL : WrH;
    for (int ktb = 0; ktb < 2; ++ktb) {
      if (t || ktb) __syncthreads();
      const int kt = ktb << 6;
#pragma unroll
      for (int c = 0; c < 4; ++c) {
        int flat = c * 256 + tid;
        int row = flat >> 3, kg = flat & 7;
        int swz = (kg ^ (row & 7)) << 3;
        int grow = bm + row;
        if (grow >= N) grow = N - 1;
        *(int4*)(&As[row * 64 + swz]) = *(const int4*)(xH + (size_t)grow * DIM + kt + kg * 8);
        *(int4*)(&Bs[row * 64 + swz]) = *(const int4*)(Wp + (size_t)row * DIM + kt + kg * 8);
      }
      __syncthreads();
#pragma unroll
      for (int ks = 0; ks < 2; ++ks) {
        bf16x8 af[4], bfr[4];
        int kg = (ks << 2) + quad;
#pragma unroll
        for (int i = 0; i < 4; ++i) {
          int ar = (wm << 6) + (i << 4) + l15;
          af[i] = *(const bf16x8*)(&As[ar * 64 + ((kg ^ (ar & 7)) << 3)]);
          int br = (wn << 6) + (i << 4) + l15;
          bfr[i] = *(const bf16x8*)(&Bs[br * 64 + ((kg ^ (br & 7)) << 3)]);
        }
#pragma unroll
        for (int i = 0; i < 4; ++i)
#pragma unroll
          for (int j = 0; j < 4; ++j)
            acc[i][j] = __builtin_amdgcn_mfma_f32_16x16x32_bf16(af[i], bfr[j], acc[i][j], 0, 0, 0);
      }
    }
  }

#pragma unroll
  for (int i = 0; i < 4; ++i)
#pragma unroll
    for (int rr = 0; rr < 4; ++rr) {
      int grow = bm + (wm << 6) + (i << 4) + (quad << 2) + rr;
      if (grow < N) {
#pragma unroll
        for (int j = 0; j < 4; ++j)
          hr[(size_t)grow * DIM + (wn << 6) + (j << 4) + l15] = f2bf(acc[i][j][rr]);
      }
    }
}

// ---------------- wave-per-node gather-aggregate (hi only) ----------------
__global__ __launch_bounds__(256) void gather_wave_kernel(
    const ushort* __restrict__ featH, const int* __restrict__ csr_src,
    const unsigned* __restrict__ off, const float* __restrict__ dinv,
    ushort* __restrict__ aggH, int N) {
  const int node = (blockIdx.x * 256 + threadIdx.x) >> 6;
  if (node >= N) return;
  const int lane = threadIdx.x & 63;
  const int eslot = lane >> 4;
  const int col = lane & 15;
  const unsigned beg = off[node], end = off[node + 1];
  const ushort* fbase = featH + col * 8;

  float acc[8];
#pragma unroll
  for (int t = 0; t < 8; ++t) acc[t] = 0.f;

  auto accum = [&](int4 v) {
    unsigned w0 = (unsigned)v.x, w1 = (unsigned)v.y, w2 = (unsigned)v.z, w3 = (unsigned)v.w;
    acc[0] += __uint_as_float(w0 << 16);
    acc[1] += __uint_as_float(w0 & 0xFFFF0000u);
    acc[2] += __uint_as_float(w1 << 16);
    acc[3] += __uint_as_float(w1 & 0xFFFF0000u);
    acc[4] += __uint_as_float(w2 << 16);
    acc[5] += __uint_as_float(w2 & 0xFFFF0000u);
    acc[6] += __uint_as_float(w3 << 16);
    acc[7] += __uint_as_float(w3 & 0xFFFF0000u);
  };

  unsigned base = beg;
  for (; base + 16 <= end; base += 16) {
    int s0 = csr_src[base + eslot];
    int s1 = csr_src[base + 4 + eslot];
    int s2 = csr_src[base + 8 + eslot];
    int s3 = csr_src[base + 12 + eslot];
    int4 v0 = *(const int4*)(fbase + (size_t)s0 * DIM);
    int4 v1 = *(const int4*)(fbase + (size_t)s1 * DIM);
    int4 v2 = *(const int4*)(fbase + (size_t)s2 * DIM);
    int4 v3 = *(const int4*)(fbase + (size_t)s3 * DIM);
    accum(v0); accum(v1); accum(v2); accum(v3);
  }
  for (; base + 8 <= end; base += 8) {
    int s0 = csr_src[base + eslot];
    int s1 = csr_src[base + 4 + eslot];
    int4 v0 = *(const int4*)(fbase + (size_t)s0 * DIM);
    int4 v1 = *(const int4*)(fbase + (size_t)s1 * DIM);
    accum(v0); accum(v1);
  }
  for (unsigned e = base + eslot; e < end; e += 4) {
    int s = csr_src[e];
    int4 v = *(const int4*)(fbase + (size_t)s * DIM);
    accum(v);
  }

#pragma unroll
  for (int t = 0; t < 8; ++t) {
    acc[t] += __shfl_xor(acc[t], 32, 64);
    acc[t] += __shfl_xor(acc[t], 16, 64);
  }

  if (eslot == 0) {
    float di = dinv[node];
    unsigned ph[4];
#pragma unroll
    for (int t = 0; t < 4; ++t) {
      ph[t] = (unsigned)f2bf(acc[2 * t] * di) | ((unsigned)f2bf(acc[2 * t + 1] * di) << 16);
    }
    *(int4*)(aggH + (size_t)node * DIM + col * 8) =
        make_int4((int)ph[0], (int)ph[1], (int)ph[2], (int)ph[3]);
  }
}

// ---------------- MFMA SAGE layer ----------------
// addin != nullptr (layer 1): out = relu( aggH@(WlH+WlL) + addin + b ) — 2 segment groups.
// addin == nullptr (layer 2): out = relu( aggH@(WlH+WlL) + xH@(WrH+WrL) + b ) — 4 groups,
// plus optional fused lin3 -> y. outH optional.
__global__ __launch_bounds__(256) void sage_mfma_kernel(
    const ushort* __restrict__ aggH, const ushort* xH,
    const ushort* __restrict__ WlH, const ushort* __restrict__ WlL,
    const ushort* __restrict__ WrH, const ushort* __restrict__ WrL,
    const float* __restrict__ bias,
    const float* __restrict__ W3l, const float* __restrict__ W3r,
    const ushort* __restrict__ addin,
    ushort* __restrict__ outH, float* __restrict__ y, int N) {
  __shared__ ushort As[128 * 64];      // 16 KB
  __shared__ ushort Bs[2 * 128 * 64];  // 32 KB: [0]=W_H tile, [1]=W_L tile

  const int tid = threadIdx.x;
  const int bm = blockIdx.x * 128;
  const int wave = tid >> 6;
  const int lane = tid & 63;
  const int l15 = lane & 15;
  const int quad = lane >> 4;
  const int wm = wave >> 1;
  const int wn = wave & 1;

  f32x4 acc[4][4];
#pragma unroll
  for (int i = 0; i < 4; ++i)
#pragma unroll
    for (int j = 0; j < 4; ++j) acc[i][j] = (f32x4){0.f, 0.f, 0.f, 0.f};

  const int ng = addin ? 2 : 4;
  for (int g = 0; g < ng; ++g) {
    const ushort* Ap = (g < 2) ? aggH : xH;
    const ushort* WH = (g < 2) ? WlH : WrH;
    const ushort* WL = (g < 2) ? WlL : WrL;
    const int kt = (g & 1) << 6;
    __syncthreads();
#pragma unroll
    for (int c = 0; c < 4; ++c) {
      int flat = c * 256 + tid;
      int row = flat >> 3;
      int kg = flat & 7;
      int swz = (kg ^ (row & 7)) << 3;
      int grow = bm + row;
      if (grow >= N) grow = N - 1;
      *(int4*)(&As[row * 64 + swz]) = *(const int4*)(Ap + (size_t)grow * DIM + kt + kg * 8);
    }
#pragma unroll
    for (int c = 0; c < 8; ++c) {
      int flat = c * 256 + tid;          // 0..2047
      int tbl = flat >> 10;
      int row = (flat >> 3) & 127;
      int kg = flat & 7;
      int swz = (kg ^ (row & 7)) << 3;
      const ushort* Wp = tbl ? WL : WH;
      *(int4*)(&Bs[tbl * 8192 + row * 64 + swz]) =
          *(const int4*)(Wp + (size_t)row * DIM + kt + kg * 8);
    }
    __syncthreads();
#pragma unroll
    for (int ks = 0; ks < 2; ++ks) {
      bf16x8 af[4], bh[4], bl[4];
      int kg = (ks << 2) + quad;
#pragma unroll
      for (int i = 0; i < 4; ++i) {
        int ar = (wm << 6) + (i << 4) + l15;
        af[i] = *(const bf16x8*)(&As[ar * 64 + ((kg ^ (ar & 7)) << 3)]);
        int br = (wn << 6) + (i << 4) + l15;
        int bo = br * 64 + ((kg ^ (br & 7)) << 3);
        bh[i] = *(const bf16x8*)(&Bs[bo]);
        bl[i] = *(const bf16x8*)(&Bs[8192 + bo]);
      }
#pragma unroll
      for (int i = 0; i < 4; ++i)
#pragma unroll
        for (int j = 0; j < 4; ++j) {
          acc[i][j] = __builtin_amdgcn_mfma_f32_16x16x32_bf16(af[i], bh[j], acc[i][j], 0, 0, 0);
          acc[i][j] = __builtin_amdgcn_mfma_f32_16x16x32_bf16(af[i], bl[j], acc[i][j], 0, 0, 0);
        }
    }
  }

  __syncthreads();  // As/Bs dead; alias epilogue buffers onto As
  float* WcF = reinterpret_cast<float*>(As);        // [128][4] = 2 KB
  float* YpF = reinterpret_cast<float*>(As) + 512;  // [128][4][2] = 4 KB

  if (W3l) {
    for (int t = tid; t < 512; t += 256) {
      int col = t >> 2, c = t & 3;
      WcF[t] = (c < 2) ? W3l[col * 2 + c] : W3r[col * 2 + (c - 2)];
    }
    __syncthreads();
  }

  float bv[4];
#pragma unroll
  for (int j = 0; j < 4; ++j) bv[j] = bias[(wn << 6) + (j << 4) + l15];

#pragma unroll
  for (int i = 0; i < 4; ++i) {
#pragma unroll
    for (int r = 0; r < 4; ++r) {
      const int rowl = (wm << 6) + (i << 4) + (quad << 2) + r;
      const int grow = bm + rowl;
      float p0 = 0.f, p1 = 0.f, p2 = 0.f, p3 = 0.f;
#pragma unroll
      for (int j = 0; j < 4; ++j) {
        int col = (wn << 6) + (j << 4) + l15;
        float v = acc[i][j][r] + bv[j];
        if (addin && grow < N) v += bf2f(addin[(size_t)grow * DIM + col]);
        v = fmaxf(v, 0.f);
        ushort h = f2bf(v);
        if (outH && grow < N) outH[(size_t)grow * DIM + col] = h;
        if (W3l) {
          float qv = bf2f(h);
          p0 += qv * WcF[col * 4 + 0];
          p1 += qv * WcF[col * 4 + 1];
          p2 += qv * WcF[col * 4 + 2];
          p3 += qv * WcF[col * 4 + 3];
        }
      }
      if (W3l) {
#pragma unroll
        for (int o = 1; o < 16; o <<= 1) {
          p0 += __shfl_xor(p0, o, 64);
          p1 += __shfl_xor(p1, o, 64);
          p2 += __shfl_xor(p2, o, 64);
          p3 += __shfl_xor(p3, o, 64);
        }
        if (l15 == 0) {
          YpF[(rowl * 4 + 0) * 2 + wn] = p0;
          YpF[(rowl * 4 + 1) * 2 + wn] = p1;
          YpF[(rowl * 4 + 2) * 2 + wn] = p2;
          YpF[(rowl * 4 + 3) * 2 + wn] = p3;
        }
      }
    }
  }

  if (W3l) {
    __syncthreads();
    for (int t = tid; t < 512; t += 256) {
      int grow = bm + (t >> 2);
      if (grow < N) y[(size_t)grow * 4 + (t & 3)] = YpF[t * 2 + 0] + YpF[t * 2 + 1];
    }
  }
}

// ---------------- layer 3: 2-dim CSR gather + bias + relu + log_softmax ----------------
__global__ __launch_bounds__(256) void final3_kernel(const float* __restrict__ y,
                                                     const int* __restrict__ csr_src,
                                                     const unsigned* __restrict__ off,
                                                     const float* __restrict__ dinv,
                                                     const float* __restrict__ b3,
                                                     float* __restrict__ out, int N) {
  int n = blockIdx.x * 256 + threadIdx.x;
  if (n >= N) return;
  unsigned beg = off[n], end = off[n + 1];
  float s0 = 0.f, s1 = 0.f;
  for (unsigned e = beg; e < end; ++e) {
    int s = csr_src[e];
    float2 v = *reinterpret_cast<const float2*>(&y[(size_t)s * 4]);
    s0 += v.x; s1 += v.y;
  }
  float di = dinv[n];
  float o0 = fmaxf(s0 * di + y[(size_t)n * 4 + 2] + b3[0], 0.f);
  float o1 = fmaxf(s1 * di + y[(size_t)n * 4 + 3] + b3[1], 0.f);
  float m = fmaxf(o0, o1);
  float l = m + logf(expf(o0 - m) + expf(o1 - m));
  out[n * 2 + 0] = o0 - l;
  out[n * 2 + 1] = o1 - l;
}

extern "C" void kernel_launch(void* const* d_in, const int* in_sizes, int n_in,
                              void* d_out, int out_size, void* d_ws, size_t ws_size,
                              hipStream_t stream) {
  const float* x   = (const float*)d_in[0];
  const int*   ei  = (const int*)d_in[1];
  const float* W1l = (const float*)d_in[2];
  const float* W1r = (const float*)d_in[3];
  const float* b1  = (const float*)d_in[4];
  const float* W2l = (const float*)d_in[5];
  const float* W2r = (const float*)d_in[6];
  const float* b2  = (const float*)d_in[7];
  const float* W3l = (const float*)d_in[8];
  const float* W3r = (const float*)d_in[9];
  const float* b3  = (const float*)d_in[10];

  const int N = in_sizes[0] / DIM;  // 100000
  const int E = in_sizes[1] / 2;    // 1600000
  const int* src = ei;
  const int* dst = ei + E;
  const int B = (N + 255) / 256;

  char* ws = (char*)d_ws;
  size_t off_b = 0;
  auto alloc = [&](size_t bytes) {
    void* p = ws + off_b;
    off_b = (off_b + bytes + 255) & ~(size_t)255;
    return p;
  };
  unsigned* deg     = (unsigned*)alloc((size_t)N * 4);
  unsigned* excl    = (unsigned*)alloc((size_t)N * 4);
  unsigned* partial = (unsigned*)alloc((size_t)B * 4);
  unsigned* offs    = (unsigned*)alloc((size_t)(N + 1) * 4);
  unsigned* rank    = (unsigned*)alloc((size_t)E * 4);
  int*      csr_src = (int*)alloc((size_t)E * 4);
  float*    dinv    = (float*)alloc((size_t)N * 4);
  ushort*   xH      = (ushort*)alloc((size_t)N * DIM * 2);
  ushort*   hbuf    = (ushort*)alloc((size_t)N * DIM * 2);
  ushort*   aggH    = (ushort*)alloc((size_t)N * DIM * 2);
  ushort*   wtabs   = (ushort*)alloc((size_t)8 * 16384 * 2);
  float*    y       = (float*)alloc((size_t)N * 4 * 4);

  // ---- fused prep: hist_rank || cast || wsplit, interleaved ----
  const int H = (E + 255) / 256;                           // 6250
  const int C = (int)(((size_t)N * DIM / 4 + 255) / 256);  // 12500
  const int third = (H > (C + 257) / 2) ? H : (C + 257) / 2;
  hipMemsetAsync(deg, 0, (size_t)N * 4, stream);
  prep_kernel<<<third * 3, 256, 0, stream>>>(dst, deg, rank, E, x, xH, (long)N * DIM,
                                             W1l, W1r, W2l, W2r, wtabs, H, C);

  // ---- scan ----
  scan_block_kernel<<<B, 256, 0, stream>>>(deg, excl, partial, dinv, N);
  scan_partials_kernel<<<1, 256, 0, stream>>>(partial, B);

  const ushort* W1lH = wtabs;           const ushort* W1lL = wtabs + 16384;
  const ushort* W1rH = wtabs + 32768;   const ushort* W1rL = wtabs + 49152;
  const ushort* W2lH = wtabs + 65536;   const ushort* W2lL = wtabs + 81920;
  const ushort* W2rH = wtabs + 98304;   const ushort* W2rL = wtabs + 114688;

  const int G = (N + 127) / 128;  // 782 GEMM blocks
  const int A = (N + 256) / 256;  // add_offsets blocks (covers i==N)

  // ---- fused: csr_fill || add_offsets || hr1 = xH @ W1r ----
  {
    const int F = (E + 255) / 256;  // 6250 fill blocks
    int Q = (F + 4) / 5;
    if (Q < G + A) Q = G + A;
    fill_linr_kernel<<<Q * 6, 256, 0, stream>>>(src, dst, rank, excl, partial, offs, csr_src,
                                                E, N, xH, W1rH, W1rL, hbuf, G, A);
  }

  const int gather_grid = (N + 3) / 4;  // one wave per node

  // ---- layer 1: h1 = relu(agg@W1l + hr1 + b1) in-place over xH ----
  gather_wave_kernel<<<gather_grid, 256, 0, stream>>>(xH, csr_src, offs, dinv, aggH, N);
  sage_mfma_kernel<<<G, 256, 0, stream>>>(aggH, nullptr, W1lH, W1lL, nullptr, nullptr, b1,
                                          nullptr, nullptr, hbuf, xH, nullptr, N);
  // ---- layer 2: y only (fused lin3; no h2 store) ----
  gather_wave_kernel<<<gather_grid, 256, 0, stream>>>(xH, csr_src, offs, dinv, aggH, N);
  sage_mfma_kernel<<<G, 256, 0, stream>>>(aggH, xH, W2lH, W2lL, W2rH, W2rL, b2,
                                          W3l, W3r, nullptr, nullptr, y, N);
  // ---- layer 3 ----
  final3_kernel<<<(N + 255) / 256, 256, 0, stream>>>(y, csr_src, offs, dinv, b3, (float*)d_out, N);
}

// Round 12
// 397.480 us; speedup vs baseline: 1.4508x; 1.0886x over previous
//
#include <hip/hip_runtime.h>
#include <hip/hip_bf16.h>
#include <math.h>

#define DIM 128

typedef __attribute__((ext_vector_type(8))) short bf16x8;
typedef __attribute__((ext_vector_type(4))) float f32x4;

__device__ __forceinline__ ushort f2bf(float f) {  // RTNE
  unsigned u = __float_as_uint(f);
  return (ushort)((u + 0x7FFFu + ((u >> 16) & 1u)) >> 16);
}
__device__ __forceinline__ float bf2f(ushort h) {
  return __uint_as_float(((unsigned)h) << 16);
}

// ---------------- fused prep: hist_rank || cast || wsplit, INTERLEAVED ----------------
__global__ __launch_bounds__(256) void prep_kernel(
    const int* __restrict__ dst, unsigned* __restrict__ deg, unsigned* __restrict__ rank, int E,
    const float* __restrict__ x, ushort* __restrict__ xh, long total,
    const float* __restrict__ W1l, const float* __restrict__ W1r,
    const float* __restrict__ W2l, const float* __restrict__ W2r,
    ushort* __restrict__ tabs, int H, int C) {
  const int bid = blockIdx.x;
  const int r = bid % 3;
  const int q = bid / 3;
  if (r == 0) {
    if (q < H) {
      int gid = q * 256 + threadIdx.x;
      if (gid < E) rank[gid] = atomicAdd(&deg[dst[gid]], 1u);
    }
    return;
  }
  int id2 = q * 2 + (r - 1);
  if (id2 < C) {
    long i = ((long)id2 * 256 + threadIdx.x) * 4;
    if (i >= total) return;
    float4 v = *(const float4*)(x + i);
    uint2 Hh;
    Hh.x = (unsigned)f2bf(v.x) | ((unsigned)f2bf(v.y) << 16);
    Hh.y = (unsigned)f2bf(v.z) | ((unsigned)f2bf(v.w) << 16);
    *(uint2*)(xh + i) = Hh;
    return;
  }
  id2 -= C;
  if (id2 >= 256) return;
  // wsplit role: transpose + bf16 cast (hi only — weight-lo path dropped, see R12 note)
  int m = id2 >> 6;
  const float* W = (m == 0) ? W1l : (m == 1) ? W1r : (m == 2) ? W2l : W2r;
  ushort* Ht = tabs + (size_t)m * 16384;
  int idx = (id2 & 63) * 256 + threadIdx.x;  // 0..16383
  int k = idx >> 7, n = idx & 127;
  Ht[n * DIM + k] = f2bf(W[idx]);
}

// ---------------- two-level exclusive scan over deg (+ fused dinv) ----------------
__global__ __launch_bounds__(256) void scan_block_kernel(const unsigned* __restrict__ deg,
                                                         unsigned* __restrict__ excl,
                                                         unsigned* __restrict__ partial,
                                                         float* __restrict__ dinv, int N) {
  __shared__ unsigned s[256];
  int i = blockIdx.x * 256 + threadIdx.x;
  unsigned v = (i < N) ? deg[i] : 0u;
  if (i < N) dinv[i] = 1.0f / fmaxf((float)v, 1.0f);
  s[threadIdx.x] = v;
  __syncthreads();
#pragma unroll
  for (int d = 1; d < 256; d <<= 1) {
    unsigned t = (threadIdx.x >= d) ? s[threadIdx.x - d] : 0u;
    __syncthreads();
    s[threadIdx.x] += t;
    __syncthreads();
  }
  if (i < N) excl[i] = s[threadIdx.x] - v;
  if (threadIdx.x == 255) partial[blockIdx.x] = s[255];
}

__global__ __launch_bounds__(256) void scan_partials_kernel(unsigned* __restrict__ partial, int B) {
  __shared__ unsigned s[256];
  __shared__ unsigned carry;
  if (threadIdx.x == 0) carry = 0u;
  __syncthreads();
  for (int base = 0; base < B; base += 256) {
    int i = base + threadIdx.x;
    unsigned v = (i < B) ? partial[i] : 0u;
    s[threadIdx.x] = v;
    __syncthreads();
#pragma unroll
    for (int d = 1; d < 256; d <<= 1) {
      unsigned t = (threadIdx.x >= d) ? s[threadIdx.x - d] : 0u;
      __syncthreads();
      s[threadIdx.x] += t;
      __syncthreads();
    }
    if (i < B) partial[i] = carry + s[threadIdx.x] - v;
    __syncthreads();
    if (threadIdx.x == 0) carry += s[255];
    __syncthreads();
  }
}

__global__ __launch_bounds__(256) void add_offsets_kernel(const unsigned* __restrict__ excl,
                                                          const unsigned* __restrict__ partial,
                                                          unsigned* __restrict__ off, int N, int E) {
  int i = blockIdx.x * 256 + threadIdx.x;
  if (i < N) off[i] = excl[i] + partial[i >> 8];
  if (i == N) off[N] = (unsigned)E;
}

// ---------------- CSR fill: atomic-free ----------------
__global__ __launch_bounds__(256) void csr_fill_kernel(const int* __restrict__ src,
                                                       const int* __restrict__ dst,
                                                       const unsigned* __restrict__ rank,
                                                       const unsigned* __restrict__ off,
                                                       int* __restrict__ csr_src, int E) {
  int e = blockIdx.x * 256 + threadIdx.x;
  if (e >= E) return;
  csr_src[off[dst[e]] + rank[e]] = src[e];
}

// ---------------- wave-per-node gather-aggregate (hi only) ----------------
__global__ __launch_bounds__(256) void gather_wave_kernel(
    const ushort* __restrict__ featH, const int* __restrict__ csr_src,
    const unsigned* __restrict__ off, const float* __restrict__ dinv,
    ushort* __restrict__ aggH, int N) {
  const int node = (blockIdx.x * 256 + threadIdx.x) >> 6;
  if (node >= N) return;
  const int lane = threadIdx.x & 63;
  const int eslot = lane >> 4;
  const int col = lane & 15;
  const unsigned beg = off[node], end = off[node + 1];
  const ushort* fbase = featH + col * 8;

  float acc[8];
#pragma unroll
  for (int t = 0; t < 8; ++t) acc[t] = 0.f;

  auto accum = [&](int4 v) {
    unsigned w0 = (unsigned)v.x, w1 = (unsigned)v.y, w2 = (unsigned)v.z, w3 = (unsigned)v.w;
    acc[0] += __uint_as_float(w0 << 16);
    acc[1] += __uint_as_float(w0 & 0xFFFF0000u);
    acc[2] += __uint_as_float(w1 << 16);
    acc[3] += __uint_as_float(w1 & 0xFFFF0000u);
    acc[4] += __uint_as_float(w2 << 16);
    acc[5] += __uint_as_float(w2 & 0xFFFF0000u);
    acc[6] += __uint_as_float(w3 << 16);
    acc[7] += __uint_as_float(w3 & 0xFFFF0000u);
  };

  unsigned base = beg;
  for (; base + 16 <= end; base += 16) {
    int s0 = csr_src[base + eslot];
    int s1 = csr_src[base + 4 + eslot];
    int s2 = csr_src[base + 8 + eslot];
    int s3 = csr_src[base + 12 + eslot];
    int4 v0 = *(const int4*)(fbase + (size_t)s0 * DIM);
    int4 v1 = *(const int4*)(fbase + (size_t)s1 * DIM);
    int4 v2 = *(const int4*)(fbase + (size_t)s2 * DIM);
    int4 v3 = *(const int4*)(fbase + (size_t)s3 * DIM);
    accum(v0); accum(v1); accum(v2); accum(v3);
  }
  for (; base + 8 <= end; base += 8) {
    int s0 = csr_src[base + eslot];
    int s1 = csr_src[base + 4 + eslot];
    int4 v0 = *(const int4*)(fbase + (size_t)s0 * DIM);
    int4 v1 = *(const int4*)(fbase + (size_t)s1 * DIM);
    accum(v0); accum(v1);
  }
  for (unsigned e = base + eslot; e < end; e += 4) {
    int s = csr_src[e];
    int4 v = *(const int4*)(fbase + (size_t)s * DIM);
    accum(v);
  }

#pragma unroll
  for (int t = 0; t < 8; ++t) {
    acc[t] += __shfl_xor(acc[t], 32, 64);
    acc[t] += __shfl_xor(acc[t], 16, 64);
  }

  if (eslot == 0) {
    float di = dinv[node];
    unsigned ph[4];
#pragma unroll
    for (int t = 0; t < 4; ++t) {
      ph[t] = (unsigned)f2bf(acc[2 * t] * di) | ((unsigned)f2bf(acc[2 * t + 1] * di) << 16);
    }
    *(int4*)(aggH + (size_t)node * DIM + col * 8) =
        make_int4((int)ph[0], (int)ph[1], (int)ph[2], (int)ph[3]);
  }
}

// ---------------- MFMA SAGE layer (bf16 weights, no lo-compensation) ----------------
// out = relu( aggH@WlH + xH@WrH + b ); optional fused lin3 -> y. 4 rounds of
// (stage A 16KB + stage B 16KB + 32 MFMA). LDS 32 KB -> 5 blocks/CU.
__global__ __launch_bounds__(256) void sage_mfma_kernel(
    const ushort* __restrict__ aggH, const ushort* xH,
    const ushort* __restrict__ WlH, const ushort* __restrict__ WrH,
    const float* __restrict__ bias,
    const float* __restrict__ W3l, const float* __restrict__ W3r,
    ushort* __restrict__ outH, float* __restrict__ y, int N) {
  __shared__ ushort As[128 * 64];  // 16 KB
  __shared__ ushort Bs[128 * 64];  // 16 KB

  const int tid = threadIdx.x;
  const int bm = blockIdx.x * 128;
  const int wave = tid >> 6;
  const int lane = tid & 63;
  const int l15 = lane & 15;
  const int quad = lane >> 4;
  const int wm = wave >> 1;
  const int wn = wave & 1;

  f32x4 acc[4][4];
#pragma unroll
  for (int i = 0; i < 4; ++i)
#pragma unroll
    for (int j = 0; j < 4; ++j) acc[i][j] = (f32x4){0.f, 0.f, 0.f, 0.f};

  for (int g = 0; g < 4; ++g) {
    const ushort* Ap = (g < 2) ? aggH : xH;
    const ushort* Wp = (g < 2) ? WlH : WrH;
    const int kt = (g & 1) << 6;
    __syncthreads();
#pragma unroll
    for (int c = 0; c < 4; ++c) {
      int flat = c * 256 + tid;
      int row = flat >> 3;
      int kg = flat & 7;
      int swz = (kg ^ (row & 7)) << 3;
      int grow = bm + row;
      if (grow >= N) grow = N - 1;
      *(int4*)(&As[row * 64 + swz]) = *(const int4*)(Ap + (size_t)grow * DIM + kt + kg * 8);
      *(int4*)(&Bs[row * 64 + swz]) = *(const int4*)(Wp + (size_t)row * DIM + kt + kg * 8);
    }
    __syncthreads();
#pragma unroll
    for (int ks = 0; ks < 2; ++ks) {
      bf16x8 af[4], bfr[4];
      int kg = (ks << 2) + quad;
#pragma unroll
      for (int i = 0; i < 4; ++i) {
        int ar = (wm << 6) + (i << 4) + l15;
        af[i] = *(const bf16x8*)(&As[ar * 64 + ((kg ^ (ar & 7)) << 3)]);
        int br = (wn << 6) + (i << 4) + l15;
        bfr[i] = *(const bf16x8*)(&Bs[br * 64 + ((kg ^ (br & 7)) << 3)]);
      }
#pragma unroll
      for (int i = 0; i < 4; ++i)
#pragma unroll
        for (int j = 0; j < 4; ++j)
          acc[i][j] = __builtin_amdgcn_mfma_f32_16x16x32_bf16(af[i], bfr[j], acc[i][j], 0, 0, 0);
    }
  }

  __syncthreads();  // As/Bs dead; alias epilogue buffers onto As
  float* WcF = reinterpret_cast<float*>(As);        // [128][4] = 2 KB
  float* YpF = reinterpret_cast<float*>(As) + 512;  // [128][4][2] = 4 KB

  if (W3l) {
    for (int t = tid; t < 512; t += 256) {
      int col = t >> 2, c = t & 3;
      WcF[t] = (c < 2) ? W3l[col * 2 + c] : W3r[col * 2 + (c - 2)];
    }
    __syncthreads();
  }

  float bv[4];
#pragma unroll
  for (int j = 0; j < 4; ++j) bv[j] = bias[(wn << 6) + (j << 4) + l15];

#pragma unroll
  for (int i = 0; i < 4; ++i) {
#pragma unroll
    for (int r = 0; r < 4; ++r) {
      const int rowl = (wm << 6) + (i << 4) + (quad << 2) + r;
      const int grow = bm + rowl;
      float p0 = 0.f, p1 = 0.f, p2 = 0.f, p3 = 0.f;
#pragma unroll
      for (int j = 0; j < 4; ++j) {
        int col = (wn << 6) + (j << 4) + l15;
        float v = fmaxf(acc[i][j][r] + bv[j], 0.f);
        ushort h = f2bf(v);
        if (outH && grow < N) outH[(size_t)grow * DIM + col] = h;
        if (W3l) {
          float qv = bf2f(h);
          p0 += qv * WcF[col * 4 + 0];
          p1 += qv * WcF[col * 4 + 1];
          p2 += qv * WcF[col * 4 + 2];
          p3 += qv * WcF[col * 4 + 3];
        }
      }
      if (W3l) {
#pragma unroll
        for (int o = 1; o < 16; o <<= 1) {
          p0 += __shfl_xor(p0, o, 64);
          p1 += __shfl_xor(p1, o, 64);
          p2 += __shfl_xor(p2, o, 64);
          p3 += __shfl_xor(p3, o, 64);
        }
        if (l15 == 0) {
          YpF[(rowl * 4 + 0) * 2 + wn] = p0;
          YpF[(rowl * 4 + 1) * 2 + wn] = p1;
          YpF[(rowl * 4 + 2) * 2 + wn] = p2;
          YpF[(rowl * 4 + 3) * 2 + wn] = p3;
        }
      }
    }
  }

  if (W3l) {
    __syncthreads();
    for (int t = tid; t < 512; t += 256) {
      int grow = bm + (t >> 2);
      if (grow < N) y[(size_t)grow * 4 + (t & 3)] = YpF[t * 2 + 0] + YpF[t * 2 + 1];
    }
  }
}

// ---------------- layer 3: 2-dim CSR gather + bias + relu + log_softmax ----------------
__global__ __launch_bounds__(256) void final3_kernel(const float* __restrict__ y,
                                                     const int* __restrict__ csr_src,
                                                     const unsigned* __restrict__ off,
                                                     const float* __restrict__ dinv,
                                                     const float* __restrict__ b3,
                                                     float* __restrict__ out, int N) {
  int n = blockIdx.x * 256 + threadIdx.x;
  if (n >= N) return;
  unsigned beg = off[n], end = off[n + 1];
  float s0 = 0.f, s1 = 0.f;
  for (unsigned e = beg; e < end; ++e) {
    int s = csr_src[e];
    float2 v = *reinterpret_cast<const float2*>(&y[(size_t)s * 4]);
    s0 += v.x; s1 += v.y;
  }
  float di = dinv[n];
  float o0 = fmaxf(s0 * di + y[(size_t)n * 4 + 2] + b3[0], 0.f);
  float o1 = fmaxf(s1 * di + y[(size_t)n * 4 + 3] + b3[1], 0.f);
  float m = fmaxf(o0, o1);
  float l = m + logf(expf(o0 - m) + expf(o1 - m));
  out[n * 2 + 0] = o0 - l;
  out[n * 2 + 1] = o1 - l;
}

extern "C" void kernel_launch(void* const* d_in, const int* in_sizes, int n_in,
                              void* d_out, int out_size, void* d_ws, size_t ws_size,
                              hipStream_t stream) {
  const float* x   = (const float*)d_in[0];
  const int*   ei  = (const int*)d_in[1];
  const float* W1l = (const float*)d_in[2];
  const float* W1r = (const float*)d_in[3];
  const float* b1  = (const float*)d_in[4];
  const float* W2l = (const float*)d_in[5];
  const float* W2r = (const float*)d_in[6];
  const float* b2  = (const float*)d_in[7];
  const float* W3l = (const float*)d_in[8];
  const float* W3r = (const float*)d_in[9];
  const float* b3  = (const float*)d_in[10];

  const int N = in_sizes[0] / DIM;  // 100000
  const int E = in_sizes[1] / 2;    // 1600000
  const int* src = ei;
  const int* dst = ei + E;
  const int B = (N + 255) / 256;

  char* ws = (char*)d_ws;
  size_t off_b = 0;
  auto alloc = [&](size_t bytes) {
    void* p = ws + off_b;
    off_b = (off_b + bytes + 255) & ~(size_t)255;
    return p;
  };
  unsigned* deg     = (unsigned*)alloc((size_t)N * 4);
  unsigned* excl    = (unsigned*)alloc((size_t)N * 4);
  unsigned* partial = (unsigned*)alloc((size_t)B * 4);
  unsigned* offs    = (unsigned*)alloc((size_t)(N + 1) * 4);
  unsigned* rank    = (unsigned*)alloc((size_t)E * 4);
  int*      csr_src = (int*)alloc((size_t)E * 4);
  float*    dinv    = (float*)alloc((size_t)N * 4);
  ushort*   xH      = (ushort*)alloc((size_t)N * DIM * 2);
  ushort*   aggH    = (ushort*)alloc((size_t)N * DIM * 2);
  ushort*   wtabs   = (ushort*)alloc((size_t)4 * 16384 * 2);
  float*    y       = (float*)alloc((size_t)N * 4 * 4);

  // ---- fused prep: hist_rank || cast || wsplit, interleaved ----
  const int H = (E + 255) / 256;                           // 6250
  const int C = (int)(((size_t)N * DIM / 4 + 255) / 256);  // 12500
  const int third = (H > (C + 257) / 2) ? H : (C + 257) / 2;
  hipMemsetAsync(deg, 0, (size_t)N * 4, stream);
  prep_kernel<<<third * 3, 256, 0, stream>>>(dst, deg, rank, E, x, xH, (long)N * DIM,
                                             W1l, W1r, W2l, W2r, wtabs, H, C);

  // ---- scan + fill ----
  scan_block_kernel<<<B, 256, 0, stream>>>(deg, excl, partial, dinv, N);
  scan_partials_kernel<<<1, 256, 0, stream>>>(partial, B);
  add_offsets_kernel<<<(N + 256) / 256, 256, 0, stream>>>(excl, partial, offs, N, E);
  csr_fill_kernel<<<(E + 255) / 256, 256, 0, stream>>>(src, dst, rank, offs, csr_src, E);

  const ushort* W1lH = wtabs;
  const ushort* W1rH = wtabs + 16384;
  const ushort* W2lH = wtabs + 32768;
  const ushort* W2rH = wtabs + 49152;

  const int G = (N + 127) / 128;
  const int gather_grid = (N + 3) / 4;  // one wave per node

  // ---- layer 1: h1 = relu(agg@W1l + x@W1r + b1) in-place over xH ----
  gather_wave_kernel<<<gather_grid, 256, 0, stream>>>(xH, csr_src, offs, dinv, aggH, N);
  sage_mfma_kernel<<<G, 256, 0, stream>>>(aggH, xH, W1lH, W1rH, b1,
                                          nullptr, nullptr, xH, nullptr, N);
  // ---- layer 2: y only (fused lin3; no h2 store) ----
  gather_wave_kernel<<<gather_grid, 256, 0, stream>>>(xH, csr_src, offs, dinv, aggH, N);
  sage_mfma_kernel<<<G, 256, 0, stream>>>(aggH, xH, W2lH, W2rH, b2,
                                          W3l, W3r, nullptr, y, N);
  // ---- layer 3 ----
  final3_kernel<<<(N + 255) / 256, 256, 0, stream>>>(y, csr_src, offs, dinv, b3, (float*)d_out, N);
}